// Round 2
// baseline (1466.818 us; speedup 1.0000x reference)
//
#include <hip/hip_runtime.h>
#include <math.h>

// TrfEdgeNetRand: 3x TransformerConv(heads=1) + ReLU + classifier on MI355X.
// R2: lean workspace (~238MB, was 388MB -> suspected d_ws overflow crash):
//  - H holds only q|k|v [N,3C]; skip goes to ping-pong S buffers; edge kernel
//    writes output in-place over skip (same-thread read-then-write, no hazard).
//  - xb aliases SB (liveness-disjoint).
//  - no eperm copy: CSR stores int2{src,eid}; edge attr read via eid (64B
//    wave-broadcast, L3-resident).
//  - src/dst clamped in setup kernels: if edge_index dtype were wrong we get
//    an absmax failure (diagnostic) instead of a GPU fault.

typedef unsigned int uint;
typedef unsigned short ushort;
typedef __bf16 bf16x8 __attribute__((ext_vector_type(8)));
typedef float f32x4 __attribute__((ext_vector_type(4)));

__device__ __forceinline__ ushort f2bf(float f) {
    uint u = __float_as_uint(f);
    u += 0x7fffu + ((u >> 16) & 1u);   // round-to-nearest-even
    return (ushort)(u >> 16);
}
__device__ __forceinline__ float bf2f(ushort h) {
    return __uint_as_float(((uint)h) << 16);
}

// ---------------- utility kernels ----------------
__global__ void k_zero(uint* p, int n) {
    int i = blockIdx.x * 256 + threadIdx.x;
    if (i < n) p[i] = 0u;
}

__global__ void k_hist(const int* __restrict__ dst, uint* __restrict__ counts, int E, int N) {
    int e = blockIdx.x * 256 + threadIdx.x;
    if (e < E) {
        int d = dst[e];
        d = (d < 0) ? 0 : (d >= N ? N - 1 : d);   // clamp: diagnostic safety
        atomicAdd(&counts[d], 1u);
    }
}

// block sums over 1024-element chunks
__global__ void k_scan1(const uint* __restrict__ counts, uint* __restrict__ bsum, int n) {
    __shared__ uint sm[256];
    int tid = threadIdx.x;
    int base = blockIdx.x * 1024 + tid * 4;
    uint s = 0;
#pragma unroll
    for (int j = 0; j < 4; ++j)
        if (base + j < n) s += counts[base + j];
    sm[tid] = s;
    __syncthreads();
    for (int d = 128; d > 0; d >>= 1) {
        if (tid < d) sm[tid] += sm[tid + d];
        __syncthreads();
    }
    if (tid == 0) bsum[blockIdx.x] = sm[0];
}

__global__ void k_scan2(uint* bsum, int nb) {
    if (threadIdx.x == 0 && blockIdx.x == 0) {
        uint run = 0;
        for (int i = 0; i < nb; ++i) { uint v = bsum[i]; bsum[i] = run; run += v; }
    }
}

__global__ void k_scan3(const uint* __restrict__ counts, const uint* __restrict__ bsum,
                        uint* __restrict__ row_ptr, int n, int E) {
    __shared__ uint sm[256];
    int tid = threadIdx.x;
    int base = blockIdx.x * 1024 + tid * 4;
    uint local[4];
    uint s = 0;
#pragma unroll
    for (int j = 0; j < 4; ++j) {
        local[j] = (base + j < n) ? counts[base + j] : 0u;
        s += local[j];
    }
    sm[tid] = s;
    __syncthreads();
    for (int d = 1; d < 256; d <<= 1) {
        uint v = (tid >= d) ? sm[tid - d] : 0u;
        __syncthreads();
        sm[tid] += v;
        __syncthreads();
    }
    uint run = sm[tid] - s + bsum[blockIdx.x];
#pragma unroll
    for (int j = 0; j < 4; ++j)
        if (base + j < n) { row_ptr[base + j] = run; run += local[j]; }
    if (blockIdx.x == 0 && tid == 0) row_ptr[n] = (uint)E;
}

__global__ void k_fill(const int* __restrict__ ei, const uint* __restrict__ row_ptr,
                       uint* __restrict__ cursor, int2* __restrict__ srcid, int E, int N) {
    int e = blockIdx.x * 256 + threadIdx.x;
    if (e >= E) return;
    int s = ei[e];
    int d = ei[E + e];
    s = (s < 0) ? 0 : (s >= N ? N - 1 : s);   // clamp: diagnostic safety
    d = (d < 0) ? 0 : (d >= N ? N - 1 : d);
    uint idx = row_ptr[d] + atomicAdd(&cursor[d], 1u);
    srcid[idx] = make_int2(s, e);
}

__global__ void k_cvt(const float4* __restrict__ in, ushort4* __restrict__ outp, int n4) {
    int i = blockIdx.x * 256 + threadIdx.x;
    if (i >= n4) return;
    float4 v = in[i];
    ushort4 o;
    o.x = f2bf(v.x); o.y = f2bf(v.y); o.z = f2bf(v.z); o.w = f2bf(v.w);
    outp[i] = o;
}

// ---------------- weight packing ----------------
// Bp[((kt*nct + ct)*64 + lane)*8 + j] = bf16(W[kt*32 + (lane>>4)*8 + j][ct*16 + (lane&15)])
// over concatenated columns [Wq | Wk | Wv | Ws], each [128, C].
__global__ void k_packw(const float* __restrict__ Wq, const float* __restrict__ Wk,
                        const float* __restrict__ Wv, const float* __restrict__ Ws,
                        ushort* __restrict__ Bp, int C) {
    int nct = (4 * C) >> 4;
    int total = 4 * nct * 64 * 8;
    int id = blockIdx.x * 256 + threadIdx.x;
    if (id >= total) return;
    int j = id & 7;
    int rest = id >> 3;
    int lane = rest & 63;
    rest >>= 6;
    int ct = rest % nct;
    int kt = rest / nct;
    int k = kt * 32 + ((lane >> 4) << 3) + j;
    int c = (ct << 4) + (lane & 15);
    int mat = c / C, cc = c % C;
    const float* W = (mat == 0) ? Wq : (mat == 1) ? Wk : (mat == 2) ? Wv : Ws;
    Bp[id] = f2bf(W[k * C + cc]);
}

__global__ void k_bias(const float* __restrict__ bq, const float* __restrict__ bk,
                       const float* __restrict__ bv, const float* __restrict__ bs,
                       float* __restrict__ outp, int C) {
    int c = blockIdx.x * 256 + threadIdx.x;
    if (c >= 4 * C) return;
    int mat = c / C, cc = c % C;
    const float* b = (mat == 0) ? bq : (mat == 1) ? bk : (mat == 2) ? bv : bs;
    outp[c] = b[cc];
}

// ---------------- fused QKVS GEMM (bf16 MFMA) ----------------
// A: [N,128] bf16 row-major. Cols [0,3C) -> H (q|k|v), cols [3C,4C) -> S (skip).
// Block = 4 waves; block covers 16 rows x 256 cols.
__global__ __launch_bounds__(256) void k_gemm(const ushort* __restrict__ A,
                                              const ushort* __restrict__ Bp,
                                              const float* __restrict__ bias,
                                              ushort* __restrict__ H,
                                              ushort* __restrict__ S, int C) {
    int fourC = 4 * C, threeC = 3 * C;
    int lane = threadIdx.x & 63;
    int wave = threadIdx.x >> 6;
    int quad = lane >> 4;
    int r = lane & 15;
    int m0 = blockIdx.y << 4;
    int c0 = (blockIdx.x << 8) + (wave << 6);
    int nct = fourC >> 4;
    int row = m0 + r;                 // N divisible by 16 (100000 = 16*6250)
    int ct0 = c0 >> 4;

    f32x4 acc[4];
#pragma unroll
    for (int i = 0; i < 4; ++i) acc[i] = (f32x4){0.f, 0.f, 0.f, 0.f};

#pragma unroll
    for (int kk = 0; kk < 4; ++kk) {
        bf16x8 a = *(const bf16x8*)(A + (size_t)row * 128 + kk * 32 + (quad << 3));
#pragma unroll
        for (int i = 0; i < 4; ++i) {
            bf16x8 b = *(const bf16x8*)(Bp + ((size_t)((kk * nct + ct0 + i) << 6) + lane) * 8);
            acc[i] = __builtin_amdgcn_mfma_f32_16x16x32_bf16(a, b, acc[i], 0, 0, 0);
        }
    }
#pragma unroll
    for (int i = 0; i < 4; ++i) {
        int cc = c0 + (i << 4) + r;
        float bi = bias[cc];
#pragma unroll
        for (int reg = 0; reg < 4; ++reg) {
            int rr = m0 + (quad << 2) + reg;
            ushort val = f2bf(acc[i][reg] + bi);
            if (cc < threeC) H[(size_t)rr * threeC + cc] = val;
            else             S[(size_t)rr * C + (cc - threeC)] = val;
        }
    }
}

// ---------------- bf16 fragment loads ----------------
template <int VPL>
__device__ __forceinline__ void loadbf(const ushort* p, float* o);
template <>
__device__ __forceinline__ void loadbf<2>(const ushort* p, float* o) {
    uint u = *(const uint*)p;
    o[0] = bf2f((ushort)(u & 0xffffu));
    o[1] = bf2f((ushort)(u >> 16));
}
template <>
__device__ __forceinline__ void loadbf<4>(const ushort* p, float* o) {
    uint2 u = *(const uint2*)p;
    o[0] = bf2f((ushort)(u.x & 0xffffu));
    o[1] = bf2f((ushort)(u.x >> 16));
    o[2] = bf2f((ushort)(u.y & 0xffffu));
    o[3] = bf2f((ushort)(u.y >> 16));
}

// ---------------- edge attention (one wave per node, online softmax) ----------------
// H: [N,3C] bf16 (q|k|v). S: [N,C] bf16, holds skip on entry, output on exit
// (in-place per-element; same thread reads skip then writes, no hazard).
template <int C, bool RELU>
__global__ __launch_bounds__(256) void k_edge(const ushort* __restrict__ H,
                                              ushort* __restrict__ S,
                                              const uint* __restrict__ row_ptr,
                                              const int2* __restrict__ srcid,
                                              const float* __restrict__ eattr,
                                              const float* __restrict__ We,
                                              int N, int totalWaves) {
    constexpr int VPL = C / 64;
    constexpr int THREEC = 3 * C;
    int lane = threadIdx.x & 63;
    int gw = (int)((blockIdx.x * blockDim.x + threadIdx.x) >> 6);

    // We columns for this lane held in registers: we[f][j] = We[f][lane*VPL+j]
    float we[16][VPL];
#pragma unroll
    for (int f = 0; f < 16; ++f)
#pragma unroll
        for (int j = 0; j < VPL; ++j) we[f][j] = We[f * C + lane * VPL + j];

    const float scale = (C == 128) ? 0.0883883476483184f : 0.0625f;  // 1/sqrt(C)

    for (int node = gw; node < N; node += totalWaves) {
        uint beg = row_ptr[node], end = row_ptr[node + 1];
        float q[VPL];
        loadbf<VPL>(H + (size_t)node * THREEC + lane * VPL, q);
        float m = -INFINITY, l = 0.f;
        float acc[VPL];
#pragma unroll
        for (int j = 0; j < VPL; ++j) acc[j] = 0.f;

        for (uint t = beg; t < end; ++t) {
            int2 se = srcid[t];
            int src = se.x;
            const float4* ea = (const float4*)(eattr + (size_t)se.y * 16);
            float4 a0 = ea[0], a1 = ea[1], a2 = ea[2], a3 = ea[3];
            float attr[16] = {a0.x, a0.y, a0.z, a0.w, a1.x, a1.y, a1.z, a1.w,
                              a2.x, a2.y, a2.z, a2.w, a3.x, a3.y, a3.z, a3.w};
            float e[VPL];
#pragma unroll
            for (int j = 0; j < VPL; ++j) e[j] = 0.f;
#pragma unroll
            for (int f = 0; f < 16; ++f)
#pragma unroll
                for (int j = 0; j < VPL; ++j) e[j] = fmaf(attr[f], we[f][j], e[j]);

            float kv[VPL];
            loadbf<VPL>(H + (size_t)src * THREEC + C + lane * VPL, kv);
            float part = 0.f;
#pragma unroll
            for (int j = 0; j < VPL; ++j) part += q[j] * (kv[j] + e[j]);
#pragma unroll
            for (int off = 32; off > 0; off >>= 1) part += __shfl_xor(part, off);
            float alpha = part * scale;

            float mn = fmaxf(m, alpha);
            float sc = __expf(m - mn);    // m=-inf on first edge -> 0
            float p = __expf(alpha - mn);
            l = l * sc + p;

            float vv[VPL];
            loadbf<VPL>(H + (size_t)src * THREEC + 2 * C + lane * VPL, vv);
#pragma unroll
            for (int j = 0; j < VPL; ++j) acc[j] = acc[j] * sc + p * (vv[j] + e[j]);
            m = mn;
        }
        float inv = 1.f / (l + 1e-16f);   // empty segment: acc=0 -> out = skip
        float sk[VPL];
        loadbf<VPL>(S + (size_t)node * C + lane * VPL, sk);
#pragma unroll
        for (int j = 0; j < VPL; ++j) {
            float o = acc[j] * inv + sk[j];
            if (RELU) o = fmaxf(o, 0.f);
            S[(size_t)node * C + lane * VPL + j] = f2bf(o);
        }
    }
}

// ---------------- classifier: out[N,10] = h3(bf16) @ Wc + bc ----------------
__global__ void k_cls(const ushort* __restrict__ h, const float* __restrict__ Wc,
                      const float* __restrict__ bc, float* __restrict__ outp, int N) {
    int t = blockIdx.x * 256 + threadIdx.x;
    int node = t >> 4;
    int c = t & 15;
    if (node >= N || c >= 10) return;
    const ushort* hr = h + (size_t)node * 256;
    float acc = 0.f;
#pragma unroll 4
    for (int k4 = 0; k4 < 64; ++k4) {
        uint2 u = *(const uint2*)(hr + k4 * 4);
        float h0 = bf2f((ushort)(u.x & 0xffffu));
        float h1 = bf2f((ushort)(u.x >> 16));
        float h2 = bf2f((ushort)(u.y & 0xffffu));
        float h3 = bf2f((ushort)(u.y >> 16));
        int kb = k4 * 4;
        acc = fmaf(h0, Wc[(kb + 0) * 10 + c], acc);
        acc = fmaf(h1, Wc[(kb + 1) * 10 + c], acc);
        acc = fmaf(h2, Wc[(kb + 2) * 10 + c], acc);
        acc = fmaf(h3, Wc[(kb + 3) * 10 + c], acc);
    }
    outp[node * 10 + c] = acc + bc[c];
}

// ---------------- launch ----------------
extern "C" void kernel_launch(void* const* d_in, const int* in_sizes, int n_in,
                              void* d_out, int out_size, void* d_ws, size_t ws_size,
                              hipStream_t stream) {
    const float* x = (const float*)d_in[0];
    const int* ei = (const int*)d_in[1];
    const float* eattr = (const float*)d_in[2];
    const int N = in_sizes[0] / 128;
    const int E = in_sizes[1] / 2;

    const float* Wq[3], *bq[3], *Wk[3], *bk[3], *Wv[3], *bv[3], *We[3], *Ws[3], *bs[3];
    for (int li = 0; li < 3; ++li) {
        int base = 3 + li * 9;
        Wq[li] = (const float*)d_in[base + 0];
        bq[li] = (const float*)d_in[base + 1];
        Wk[li] = (const float*)d_in[base + 2];
        bk[li] = (const float*)d_in[base + 3];
        Wv[li] = (const float*)d_in[base + 4];
        bv[li] = (const float*)d_in[base + 5];
        We[li] = (const float*)d_in[base + 6];
        Ws[li] = (const float*)d_in[base + 7];
        bs[li] = (const float*)d_in[base + 8];
    }
    const float* Wc = (const float*)d_in[30];
    const float* bc = (const float*)d_in[31];

    // workspace carve (~238 MB total)
    size_t off = 0;
    char* base = (char*)d_ws;
    auto alloc = [&](size_t bytes) -> void* {
        void* p = base + off;
        off = (off + bytes + 255) & ~(size_t)255;
        return p;
    };
    ushort* SA = (ushort*)alloc((size_t)N * 256 * 2);   // 51.2 MB (skip/out ping)
    ushort* SB = (ushort*)alloc((size_t)N * 128 * 2);   // 25.6 MB (also xb)
    ushort* H  = (ushort*)alloc((size_t)N * 768 * 2);   // 153.6 MB (q|k|v max 3C)
    ushort* Bp = (ushort*)alloc(131072 * 2);            // packed weights (max 4C=1024)
    float* biasc = (float*)alloc(1024 * 4);
    uint* row_ptr = (uint*)alloc((size_t)(N + 1) * 4);
    uint* counts = (uint*)alloc((size_t)N * 4);
    uint* cursor = (uint*)alloc((size_t)N * 4);
    uint* bsum = (uint*)alloc(1024 * 4);
    int2* srcid = (int2*)alloc((size_t)E * 8);          // 6.4 MB

    ushort* xb = SB;   // alias: xb dead after layer-1 GEMM, SB first written layer-2

    int nb = (N + 1023) / 1024;

    // CSR build
    k_zero<<<(N + 255) / 256, 256, 0, stream>>>(counts, N);
    k_zero<<<(N + 255) / 256, 256, 0, stream>>>(cursor, N);
    k_hist<<<(E + 255) / 256, 256, 0, stream>>>(ei + E, counts, E, N);
    k_scan1<<<nb, 256, 0, stream>>>(counts, bsum, N);
    k_scan2<<<1, 64, 0, stream>>>(bsum, nb);
    k_scan3<<<nb, 256, 0, stream>>>(counts, bsum, row_ptr, N, E);
    k_fill<<<(E + 255) / 256, 256, 0, stream>>>(ei, row_ptr, cursor, srcid, E, N);

    // x -> bf16
    int n4 = N * 128 / 4;
    k_cvt<<<(n4 + 255) / 256, 256, 0, stream>>>((const float4*)x, (ushort4*)xb, n4);

    const int EDGE_BLOCKS = 2048;
    const int TW = EDGE_BLOCKS * 4;

    // layer 1 (C=128): A=xb, skip->SA, edge out->SA
    k_packw<<<256, 256, 0, stream>>>(Wq[0], Wk[0], Wv[0], Ws[0], Bp, 128);
    k_bias<<<2, 256, 0, stream>>>(bq[0], bk[0], bv[0], bs[0], biasc, 128);
    k_gemm<<<dim3(2, N / 16), 256, 0, stream>>>(xb, Bp, biasc, H, SA, 128);
    k_edge<128, true><<<EDGE_BLOCKS, 256, 0, stream>>>(H, SA, row_ptr, srcid, eattr, We[0], N, TW);

    // layer 2 (C=128): A=SA, skip->SB, edge out->SB
    k_packw<<<256, 256, 0, stream>>>(Wq[1], Wk[1], Wv[1], Ws[1], Bp, 128);
    k_bias<<<2, 256, 0, stream>>>(bq[1], bk[1], bv[1], bs[1], biasc, 128);
    k_gemm<<<dim3(2, N / 16), 256, 0, stream>>>(SA, Bp, biasc, H, SB, 128);
    k_edge<128, true><<<EDGE_BLOCKS, 256, 0, stream>>>(H, SB, row_ptr, srcid, eattr, We[1], N, TW);

    // layer 3 (C=256): A=SB, skip->SA, edge out->SA
    k_packw<<<512, 256, 0, stream>>>(Wq[2], Wk[2], Wv[2], Ws[2], Bp, 256);
    k_bias<<<4, 256, 0, stream>>>(bq[2], bk[2], bv[2], bs[2], biasc, 256);
    k_gemm<<<dim3(4, N / 16), 256, 0, stream>>>(SB, Bp, biasc, H, SA, 256);
    k_edge<256, false><<<EDGE_BLOCKS, 256, 0, stream>>>(H, SA, row_ptr, srcid, eattr, We[2], N, TW);

    // classifier
    k_cls<<<(N * 16 + 255) / 256, 256, 0, stream>>>(SA, Wc, bc, (float*)d_out, N);
}

// Round 3
// 1148.855 us; speedup vs baseline: 1.2768x; 1.2768x over previous
//
#include <hip/hip_runtime.h>
#include <math.h>

// TrfEdgeNetRand: 3x TransformerConv(heads=1) + ReLU + classifier on MI355X.
// R3: edge kernel restructured for latency:
//  - e-term eliminated algebraically: q.e = attr.(We q) -> g=[N,16] produced by
//    the fused MFMA GEMM (16 extra packed columns Wq@We^T); aggregated edge
//    term = (sum_e a_e attr_e)@We applied once per node from LDS-staged We.
//  - 4-edge batching: 8 independent gathers in flight, 4 pipelined butterflies,
//    one online-softmax rescale per batch.

typedef unsigned int uint;
typedef unsigned short ushort;
typedef __bf16 bf16x8 __attribute__((ext_vector_type(8)));
typedef float f32x4 __attribute__((ext_vector_type(4)));

__device__ __forceinline__ ushort f2bf(float f) {
    uint u = __float_as_uint(f);
    u += 0x7fffu + ((u >> 16) & 1u);   // round-to-nearest-even
    return (ushort)(u >> 16);
}
__device__ __forceinline__ float bf2f(ushort h) {
    return __uint_as_float(((uint)h) << 16);
}

// ---------------- utility kernels ----------------
__global__ void k_zero(uint* p, int n) {
    int i = blockIdx.x * 256 + threadIdx.x;
    if (i < n) p[i] = 0u;
}

__global__ void k_hist(const int* __restrict__ dst, uint* __restrict__ counts, int E, int N) {
    int e = blockIdx.x * 256 + threadIdx.x;
    if (e < E) {
        int d = dst[e];
        d = (d < 0) ? 0 : (d >= N ? N - 1 : d);
        atomicAdd(&counts[d], 1u);
    }
}

__global__ void k_scan1(const uint* __restrict__ counts, uint* __restrict__ bsum, int n) {
    __shared__ uint sm[256];
    int tid = threadIdx.x;
    int base = blockIdx.x * 1024 + tid * 4;
    uint s = 0;
#pragma unroll
    for (int j = 0; j < 4; ++j)
        if (base + j < n) s += counts[base + j];
    sm[tid] = s;
    __syncthreads();
    for (int d = 128; d > 0; d >>= 1) {
        if (tid < d) sm[tid] += sm[tid + d];
        __syncthreads();
    }
    if (tid == 0) bsum[blockIdx.x] = sm[0];
}

__global__ void k_scan2(uint* bsum, int nb) {
    if (threadIdx.x == 0 && blockIdx.x == 0) {
        uint run = 0;
        for (int i = 0; i < nb; ++i) { uint v = bsum[i]; bsum[i] = run; run += v; }
    }
}

__global__ void k_scan3(const uint* __restrict__ counts, const uint* __restrict__ bsum,
                        uint* __restrict__ row_ptr, int n, int E) {
    __shared__ uint sm[256];
    int tid = threadIdx.x;
    int base = blockIdx.x * 1024 + tid * 4;
    uint local[4];
    uint s = 0;
#pragma unroll
    for (int j = 0; j < 4; ++j) {
        local[j] = (base + j < n) ? counts[base + j] : 0u;
        s += local[j];
    }
    sm[tid] = s;
    __syncthreads();
    for (int d = 1; d < 256; d <<= 1) {
        uint v = (tid >= d) ? sm[tid - d] : 0u;
        __syncthreads();
        sm[tid] += v;
        __syncthreads();
    }
    uint run = sm[tid] - s + bsum[blockIdx.x];
#pragma unroll
    for (int j = 0; j < 4; ++j)
        if (base + j < n) { row_ptr[base + j] = run; run += local[j]; }
    if (blockIdx.x == 0 && tid == 0) row_ptr[n] = (uint)E;
}

__global__ void k_fill(const int* __restrict__ ei, const uint* __restrict__ row_ptr,
                       uint* __restrict__ cursor, int2* __restrict__ srcid, int E, int N) {
    int e = blockIdx.x * 256 + threadIdx.x;
    if (e >= E) return;
    int s = ei[e];
    int d = ei[E + e];
    s = (s < 0) ? 0 : (s >= N ? N - 1 : s);
    d = (d < 0) ? 0 : (d >= N ? N - 1 : d);
    uint idx = row_ptr[d] + atomicAdd(&cursor[d], 1u);
    srcid[idx] = make_int2(s, e);
}

__global__ void k_cvt(const float4* __restrict__ in, ushort4* __restrict__ outp, int n4) {
    int i = blockIdx.x * 256 + threadIdx.x;
    if (i >= n4) return;
    float4 v = in[i];
    ushort4 o;
    o.x = f2bf(v.x); o.y = f2bf(v.y); o.z = f2bf(v.z); o.w = f2bf(v.w);
    outp[i] = o;
}

// ---------------- g-projection pre-pack: Wgf[k][f] = sum_c Wq[k,c]*We[f,c] ----
__global__ void k_packg(const float* __restrict__ Wq, const float* __restrict__ bq,
                        const float* __restrict__ We, float* __restrict__ Wgf,
                        float* __restrict__ bgf, int C) {
    int id = blockIdx.x * 256 + threadIdx.x;
    if (id < 2048) {
        int k = id >> 4, f = id & 15;
        float s = 0.f;
        for (int c = 0; c < C; ++c) s = fmaf(Wq[k * C + c], We[f * C + c], s);
        Wgf[id] = s;              // layout [k*16+f]
    } else if (id < 2064) {
        int f = id - 2048;
        float s = 0.f;
        for (int c = 0; c < C; ++c) s = fmaf(bq[c], We[f * C + c], s);
        bgf[f] = s;
    }
}

// ---------------- weight packing (cols: Wq|Wk|Wv|Ws|Wg -> 4C+16) -------------
__global__ void k_packw(const float* __restrict__ Wq, const float* __restrict__ Wk,
                        const float* __restrict__ Wv, const float* __restrict__ Ws,
                        const float* __restrict__ Wgf, ushort* __restrict__ Bp, int C) {
    int nct = (4 * C + 16) >> 4;
    int total = 4 * nct * 512;
    int id = blockIdx.x * 256 + threadIdx.x;
    if (id >= total) return;
    int j = id & 7;
    int rest = id >> 3;
    int lane = rest & 63;
    rest >>= 6;
    int ct = rest % nct;
    int kt = rest / nct;
    int k = kt * 32 + ((lane >> 4) << 3) + j;
    int c = (ct << 4) + (lane & 15);
    float w;
    if (c < 4 * C) {
        int mat = c / C, cc = c % C;
        const float* W = (mat == 0) ? Wq : (mat == 1) ? Wk : (mat == 2) ? Wv : Ws;
        w = W[k * C + cc];
    } else {
        w = Wgf[k * 16 + (c - 4 * C)];
    }
    Bp[id] = f2bf(w);
}

__global__ void k_bias(const float* __restrict__ bq, const float* __restrict__ bk,
                       const float* __restrict__ bv, const float* __restrict__ bs,
                       const float* __restrict__ bgf, float* __restrict__ outp, int C) {
    int c = blockIdx.x * 256 + threadIdx.x;
    if (c >= 4 * C + 16) return;
    float v;
    if (c < 4 * C) {
        int mat = c / C, cc = c % C;
        const float* b = (mat == 0) ? bq : (mat == 1) ? bk : (mat == 2) ? bv : bs;
        v = b[cc];
    } else {
        v = bgf[c - 4 * C];
    }
    outp[c] = v;
}

// ---------------- fused QKVSG GEMM (bf16 MFMA) ----------------
// A: [N,128] bf16. Cols [0,3C)->H (q|k|v), [3C,4C)->S (skip), [4C,4C+16)->g.
__global__ __launch_bounds__(256) void k_gemm(const ushort* __restrict__ A,
                                              const ushort* __restrict__ Bp,
                                              const float* __restrict__ bias,
                                              ushort* __restrict__ H,
                                              ushort* __restrict__ S,
                                              ushort* __restrict__ g, int C) {
    int fourC = 4 * C, threeC = 3 * C;
    int P = fourC + 16;
    int nct = P >> 4;
    int lane = threadIdx.x & 63;
    int wave = threadIdx.x >> 6;
    int quad = lane >> 4;
    int r = lane & 15;
    int m0 = blockIdx.y << 4;
    int c0 = (blockIdx.x << 8) + (wave << 6);
    int ct0 = c0 >> 4;
    if (ct0 >= nct) return;
    int row = m0 + r;                 // N divisible by 16

    f32x4 acc[4];
#pragma unroll
    for (int i = 0; i < 4; ++i) acc[i] = (f32x4){0.f, 0.f, 0.f, 0.f};

#pragma unroll
    for (int kk = 0; kk < 4; ++kk) {
        bf16x8 a = *(const bf16x8*)(A + (size_t)row * 128 + kk * 32 + (quad << 3));
#pragma unroll
        for (int i = 0; i < 4; ++i) {
            if (ct0 + i < nct) {
                bf16x8 b = *(const bf16x8*)(Bp + ((size_t)((kk * nct + ct0 + i) << 6) + lane) * 8);
                acc[i] = __builtin_amdgcn_mfma_f32_16x16x32_bf16(a, b, acc[i], 0, 0, 0);
            }
        }
    }
#pragma unroll
    for (int i = 0; i < 4; ++i) {
        int cc = c0 + (i << 4) + r;
        if (cc >= P) continue;
        float bi = bias[cc];
#pragma unroll
        for (int reg = 0; reg < 4; ++reg) {
            int rr = m0 + (quad << 2) + reg;
            ushort val = f2bf(acc[i][reg] + bi);
            if (cc < threeC)      H[(size_t)rr * threeC + cc] = val;
            else if (cc < fourC)  S[(size_t)rr * C + (cc - threeC)] = val;
            else                  g[(size_t)rr * 16 + (cc - fourC)] = val;
        }
    }
}

// ---------------- bf16 fragment loads ----------------
template <int VPL>
__device__ __forceinline__ void loadbf(const ushort* p, float* o);
template <>
__device__ __forceinline__ void loadbf<2>(const ushort* p, float* o) {
    uint u = *(const uint*)p;
    o[0] = bf2f((ushort)(u & 0xffffu));
    o[1] = bf2f((ushort)(u >> 16));
}
template <>
__device__ __forceinline__ void loadbf<4>(const ushort* p, float* o) {
    uint2 u = *(const uint2*)p;
    o[0] = bf2f((ushort)(u.x & 0xffffu));
    o[1] = bf2f((ushort)(u.x >> 16));
    o[2] = bf2f((ushort)(u.y & 0xffffu));
    o[3] = bf2f((ushort)(u.y >> 16));
}

// ---------------- edge attention: 4-edge batches, online softmax -------------
// H: [N,3C] bf16 (q|k|v). S: skip on entry, output on exit. g: [N,16] bf16.
template <int C, bool RELU>
__global__ __launch_bounds__(256) void k_edge(const ushort* __restrict__ H,
                                              ushort* __restrict__ S,
                                              const ushort* __restrict__ g,
                                              const uint* __restrict__ row_ptr,
                                              const int2* __restrict__ srcid,
                                              const float* __restrict__ eattr,
                                              const float* __restrict__ We,
                                              int N, int totalWaves) {
    constexpr int VPL = C / 64;
    constexpr int THREEC = 3 * C;
    __shared__ float sWe[16 * C];
    for (int idx = threadIdx.x; idx < 16 * C; idx += 256) sWe[idx] = We[idx];
    __syncthreads();

    int lane = threadIdx.x & 63;
    int f16 = lane & 15;
    int gw = (int)((blockIdx.x * blockDim.x + threadIdx.x) >> 6);
    const float scale = (C == 128) ? 0.08838834764831843f : 0.0625f;  // 1/sqrt(C)

    for (int node = gw; node < N; node += totalWaves) {
        uint beg = row_ptr[node], end = row_ptr[node + 1];
        float q[VPL];
        loadbf<VPL>(H + (size_t)node * THREEC + lane * VPL, q);
        float gl = bf2f(g[(size_t)node * 16 + f16]);
        float m = -INFINITY, l = 0.f, w = 0.f;
        float acc[VPL];
#pragma unroll
        for (int j = 0; j < VPL; ++j) acc[j] = 0.f;

        for (uint t = beg; t < end; t += 4) {
            int rem = (int)(end - t);
            int2 se0 = srcid[t];
            int2 se1 = srcid[(rem > 1) ? t + 1 : t];
            int2 se2 = srcid[(rem > 2) ? t + 2 : t];
            int2 se3 = srcid[(rem > 3) ? t + 3 : t];
            // attr (per-lane feature, 4x replicated across lane groups)
            float at0 = eattr[(size_t)se0.y * 16 + f16];
            float at1 = eattr[(size_t)se1.y * 16 + f16];
            float at2 = eattr[(size_t)se2.y * 16 + f16];
            float at3 = eattr[(size_t)se3.y * 16 + f16];
            // 8 independent gathers in flight
            float kv0[VPL], kv1[VPL], kv2[VPL], kv3[VPL];
            float vv0[VPL], vv1[VPL], vv2[VPL], vv3[VPL];
            loadbf<VPL>(H + (size_t)se0.x * THREEC + C + lane * VPL, kv0);
            loadbf<VPL>(H + (size_t)se1.x * THREEC + C + lane * VPL, kv1);
            loadbf<VPL>(H + (size_t)se2.x * THREEC + C + lane * VPL, kv2);
            loadbf<VPL>(H + (size_t)se3.x * THREEC + C + lane * VPL, kv3);
            loadbf<VPL>(H + (size_t)se0.x * THREEC + 2 * C + lane * VPL, vv0);
            loadbf<VPL>(H + (size_t)se1.x * THREEC + 2 * C + lane * VPL, vv1);
            loadbf<VPL>(H + (size_t)se2.x * THREEC + 2 * C + lane * VPL, vv2);
            loadbf<VPL>(H + (size_t)se3.x * THREEC + 2 * C + lane * VPL, vv3);
            // logit partials; attr.g folded into 64-lane butterfly (4 replicas -> 0.25)
            float p0 = 0.25f * at0 * gl;
            float p1 = 0.25f * at1 * gl;
            float p2 = 0.25f * at2 * gl;
            float p3 = 0.25f * at3 * gl;
#pragma unroll
            for (int j = 0; j < VPL; ++j) {
                p0 = fmaf(q[j], kv0[j], p0);
                p1 = fmaf(q[j], kv1[j], p1);
                p2 = fmaf(q[j], kv2[j], p2);
                p3 = fmaf(q[j], kv3[j], p3);
            }
#pragma unroll
            for (int off = 32; off > 0; off >>= 1) {
                p0 += __shfl_xor(p0, off);
                p1 += __shfl_xor(p1, off);
                p2 += __shfl_xor(p2, off);
                p3 += __shfl_xor(p3, off);
            }
            float a0 = p0 * scale;
            float a1 = (rem > 1) ? p1 * scale : -INFINITY;
            float a2 = (rem > 2) ? p2 * scale : -INFINITY;
            float a3 = (rem > 3) ? p3 * scale : -INFINITY;
            float mn = fmaxf(m, fmaxf(fmaxf(a0, a1), fmaxf(a2, a3)));
            float sc = __expf(m - mn);        // first batch: exp(-inf)=0
            float e0 = __expf(a0 - mn);
            float e1 = __expf(a1 - mn);
            float e2 = __expf(a2 - mn);
            float e3 = __expf(a3 - mn);
            l = l * sc + ((e0 + e1) + (e2 + e3));
#pragma unroll
            for (int j = 0; j < VPL; ++j)
                acc[j] = acc[j] * sc + ((e0 * vv0[j] + e1 * vv1[j]) + (e2 * vv2[j] + e3 * vv3[j]));
            w = w * sc + ((e0 * at0 + e1 * at1) + (e2 * at2 + e3 * at3));
            m = mn;
        }
        float inv = 1.f / (l + 1e-16f);       // empty node: acc=0,w=0 -> out=skip
        float wv[16];
#pragma unroll
        for (int f = 0; f < 16; ++f) wv[f] = __shfl(w, f);
        float sk[VPL];
        loadbf<VPL>(S + (size_t)node * C + lane * VPL, sk);
#pragma unroll
        for (int j = 0; j < VPL; ++j) {
            float ew = 0.f;
#pragma unroll
            for (int f = 0; f < 16; ++f) ew = fmaf(wv[f], sWe[f * C + lane * VPL + j], ew);
            float o = (acc[j] + ew) * inv + sk[j];
            if (RELU) o = fmaxf(o, 0.f);
            S[(size_t)node * C + lane * VPL + j] = f2bf(o);
        }
    }
}

// ---------------- classifier: out[N,10] = h3(bf16) @ Wc + bc ----------------
__global__ void k_cls(const ushort* __restrict__ h, const float* __restrict__ Wc,
                      const float* __restrict__ bc, float* __restrict__ outp, int N) {
    int t = blockIdx.x * 256 + threadIdx.x;
    int node = t >> 4;
    int c = t & 15;
    if (node >= N || c >= 10) return;
    const ushort* hr = h + (size_t)node * 256;
    float acc = 0.f;
#pragma unroll 4
    for (int k4 = 0; k4 < 64; ++k4) {
        uint2 u = *(const uint2*)(hr + k4 * 4);
        float h0 = bf2f((ushort)(u.x & 0xffffu));
        float h1 = bf2f((ushort)(u.x >> 16));
        float h2 = bf2f((ushort)(u.y & 0xffffu));
        float h3 = bf2f((ushort)(u.y >> 16));
        int kb = k4 * 4;
        acc = fmaf(h0, Wc[(kb + 0) * 10 + c], acc);
        acc = fmaf(h1, Wc[(kb + 1) * 10 + c], acc);
        acc = fmaf(h2, Wc[(kb + 2) * 10 + c], acc);
        acc = fmaf(h3, Wc[(kb + 3) * 10 + c], acc);
    }
    outp[node * 10 + c] = acc + bc[c];
}

// ---------------- launch ----------------
extern "C" void kernel_launch(void* const* d_in, const int* in_sizes, int n_in,
                              void* d_out, int out_size, void* d_ws, size_t ws_size,
                              hipStream_t stream) {
    const float* x = (const float*)d_in[0];
    const int* ei = (const int*)d_in[1];
    const float* eattr = (const float*)d_in[2];
    const int N = in_sizes[0] / 128;
    const int E = in_sizes[1] / 2;

    const float* Wq[3], *bq[3], *Wk[3], *bk[3], *Wv[3], *bv[3], *We[3], *Ws[3], *bs[3];
    for (int li = 0; li < 3; ++li) {
        int base = 3 + li * 9;
        Wq[li] = (const float*)d_in[base + 0];
        bq[li] = (const float*)d_in[base + 1];
        Wk[li] = (const float*)d_in[base + 2];
        bk[li] = (const float*)d_in[base + 3];
        Wv[li] = (const float*)d_in[base + 4];
        bv[li] = (const float*)d_in[base + 5];
        We[li] = (const float*)d_in[base + 6];
        Ws[li] = (const float*)d_in[base + 7];
        bs[li] = (const float*)d_in[base + 8];
    }
    const float* Wc = (const float*)d_in[30];
    const float* bc = (const float*)d_in[31];

    // workspace carve (~243 MB)
    size_t off = 0;
    char* base = (char*)d_ws;
    auto alloc = [&](size_t bytes) -> void* {
        void* p = base + off;
        off = (off + bytes + 255) & ~(size_t)255;
        return p;
    };
    ushort* SA = (ushort*)alloc((size_t)N * 256 * 2);   // skip/out ping
    ushort* SB = (ushort*)alloc((size_t)N * 128 * 2);   // pong (also xb)
    ushort* H  = (ushort*)alloc((size_t)N * 768 * 2);   // q|k|v (max 3C)
    ushort* gbuf = (ushort*)alloc((size_t)N * 16 * 2);  // g = We.q per node
    ushort* Bp = (ushort*)alloc(140000 * 2);            // packed weights (max 4*65*512)
    float* biasc = (float*)alloc(1040 * 4);
    float* Wgf = (float*)alloc(2048 * 4);
    float* bgf = (float*)alloc(16 * 4);
    uint* row_ptr = (uint*)alloc((size_t)(N + 1) * 4);
    uint* counts = (uint*)alloc((size_t)N * 4);
    uint* cursor = (uint*)alloc((size_t)N * 4);
    uint* bsum = (uint*)alloc(1024 * 4);
    int2* srcid = (int2*)alloc((size_t)E * 8);

    ushort* xb = SB;   // alias: xb dead after layer-1 GEMM

    int nb = (N + 1023) / 1024;

    // CSR build
    k_zero<<<(N + 255) / 256, 256, 0, stream>>>(counts, N);
    k_zero<<<(N + 255) / 256, 256, 0, stream>>>(cursor, N);
    k_hist<<<(E + 255) / 256, 256, 0, stream>>>(ei + E, counts, E, N);
    k_scan1<<<nb, 256, 0, stream>>>(counts, bsum, N);
    k_scan2<<<1, 64, 0, stream>>>(bsum, nb);
    k_scan3<<<nb, 256, 0, stream>>>(counts, bsum, row_ptr, N, E);
    k_fill<<<(E + 255) / 256, 256, 0, stream>>>(ei, row_ptr, cursor, srcid, E, N);

    // x -> bf16
    int n4 = N * 128 / 4;
    k_cvt<<<(n4 + 255) / 256, 256, 0, stream>>>((const float4*)x, (ushort4*)xb, n4);

    const int EDGE_BLOCKS = 2048;
    const int TW = EDGE_BLOCKS * 4;

    for (int li = 0; li < 3; ++li) {
        int C = (li == 2) ? 256 : 128;
        int P = 4 * C + 16;
        int packTotal = 4 * (P >> 4) * 512;
        const ushort* A = (li == 0) ? xb : (li == 1) ? SA : SB;
        ushort* Sout = (li == 1) ? SB : SA;

        k_packg<<<9, 256, 0, stream>>>(Wq[li], bq[li], We[li], Wgf, bgf, C);
        k_packw<<<(packTotal + 255) / 256, 256, 0, stream>>>(Wq[li], Wk[li], Wv[li], Ws[li], Wgf, Bp, C);
        k_bias<<<(P + 255) / 256, 256, 0, stream>>>(bq[li], bk[li], bv[li], bs[li], bgf, biasc, C);
        k_gemm<<<dim3((P + 255) / 256, N / 16), 256, 0, stream>>>(A, Bp, biasc, H, Sout, gbuf, C);
        if (li == 2)
            k_edge<256, false><<<EDGE_BLOCKS, 256, 0, stream>>>(H, Sout, gbuf, row_ptr, srcid, eattr, We[li], N, TW);
        else
            k_edge<128, true><<<EDGE_BLOCKS, 256, 0, stream>>>(H, Sout, gbuf, row_ptr, srcid, eattr, We[li], N, TW);
    }

    // classifier (layer-3 output is in SA)
    k_cls<<<(N * 16 + 255) / 256, 256, 0, stream>>>(SA, Wc, bc, (float*)d_out, N);
}

// Round 4
// 1125.850 us; speedup vs baseline: 1.3029x; 1.0204x over previous
//
#include <hip/hip_runtime.h>
#include <math.h>

// TrfEdgeNetRand: 3x TransformerConv(heads=1) + ReLU + classifier on MI355X.
// R4: k_edge restructured to 16-lane groups (one edge per group):
//  - one dwordx4 gather per edge per matrix (k,v); 4 edges per load instruction
//  - attr.g folded into the 16-lane dot reduce (lane f contributes at[f]*g[f])
//  - group-local online softmax, single cross-group merge per node
//  - 2-deep software pipeline (srcid t+8, gathers t+4 in flight)
//  - no LDS; We read from global (L1-hot), f-split across groups in epilogue

typedef unsigned int uint;
typedef unsigned short ushort;
typedef __bf16 bf16x8 __attribute__((ext_vector_type(8)));
typedef float f32x4 __attribute__((ext_vector_type(4)));

__device__ __forceinline__ ushort f2bf(float f) {
    uint u = __float_as_uint(f);
    u += 0x7fffu + ((u >> 16) & 1u);   // round-to-nearest-even
    return (ushort)(u >> 16);
}
__device__ __forceinline__ float bf2f(ushort h) {
    return __uint_as_float(((uint)h) << 16);
}
__device__ __forceinline__ void unpack8(uint4 t, float* o) {
    o[0] = bf2f((ushort)(t.x & 0xffffu)); o[1] = bf2f((ushort)(t.x >> 16));
    o[2] = bf2f((ushort)(t.y & 0xffffu)); o[3] = bf2f((ushort)(t.y >> 16));
    o[4] = bf2f((ushort)(t.z & 0xffffu)); o[5] = bf2f((ushort)(t.z >> 16));
    o[6] = bf2f((ushort)(t.w & 0xffffu)); o[7] = bf2f((ushort)(t.w >> 16));
}

// ---------------- utility kernels ----------------
__global__ void k_zero(uint* p, int n) {
    int i = blockIdx.x * 256 + threadIdx.x;
    if (i < n) p[i] = 0u;
}

__global__ void k_hist(const int* __restrict__ dst, uint* __restrict__ counts, int E, int N) {
    int e = blockIdx.x * 256 + threadIdx.x;
    if (e < E) {
        int d = dst[e];
        d = (d < 0) ? 0 : (d >= N ? N - 1 : d);
        atomicAdd(&counts[d], 1u);
    }
}

__global__ void k_scan1(const uint* __restrict__ counts, uint* __restrict__ bsum, int n) {
    __shared__ uint sm[256];
    int tid = threadIdx.x;
    int base = blockIdx.x * 1024 + tid * 4;
    uint s = 0;
#pragma unroll
    for (int j = 0; j < 4; ++j)
        if (base + j < n) s += counts[base + j];
    sm[tid] = s;
    __syncthreads();
    for (int d = 128; d > 0; d >>= 1) {
        if (tid < d) sm[tid] += sm[tid + d];
        __syncthreads();
    }
    if (tid == 0) bsum[blockIdx.x] = sm[0];
}

__global__ void k_scan2(uint* bsum, int nb) {
    if (threadIdx.x == 0 && blockIdx.x == 0) {
        uint run = 0;
        for (int i = 0; i < nb; ++i) { uint v = bsum[i]; bsum[i] = run; run += v; }
    }
}

__global__ void k_scan3(const uint* __restrict__ counts, const uint* __restrict__ bsum,
                        uint* __restrict__ row_ptr, int n, int E) {
    __shared__ uint sm[256];
    int tid = threadIdx.x;
    int base = blockIdx.x * 1024 + tid * 4;
    uint local[4];
    uint s = 0;
#pragma unroll
    for (int j = 0; j < 4; ++j) {
        local[j] = (base + j < n) ? counts[base + j] : 0u;
        s += local[j];
    }
    sm[tid] = s;
    __syncthreads();
    for (int d = 1; d < 256; d <<= 1) {
        uint v = (tid >= d) ? sm[tid - d] : 0u;
        __syncthreads();
        sm[tid] += v;
        __syncthreads();
    }
    uint run = sm[tid] - s + bsum[blockIdx.x];
#pragma unroll
    for (int j = 0; j < 4; ++j)
        if (base + j < n) { row_ptr[base + j] = run; run += local[j]; }
    if (blockIdx.x == 0 && tid == 0) row_ptr[n] = (uint)E;
}

__global__ void k_fill(const int* __restrict__ ei, const uint* __restrict__ row_ptr,
                       uint* __restrict__ cursor, int2* __restrict__ srcid, int E, int N) {
    int e = blockIdx.x * 256 + threadIdx.x;
    if (e >= E) return;
    int s = ei[e];
    int d = ei[E + e];
    s = (s < 0) ? 0 : (s >= N ? N - 1 : s);
    d = (d < 0) ? 0 : (d >= N ? N - 1 : d);
    uint idx = row_ptr[d] + atomicAdd(&cursor[d], 1u);
    srcid[idx] = make_int2(s, e);
}

__global__ void k_cvt(const float4* __restrict__ in, ushort4* __restrict__ outp, int n4) {
    int i = blockIdx.x * 256 + threadIdx.x;
    if (i >= n4) return;
    float4 v = in[i];
    ushort4 o;
    o.x = f2bf(v.x); o.y = f2bf(v.y); o.z = f2bf(v.z); o.w = f2bf(v.w);
    outp[i] = o;
}

// ---------------- g-projection pre-pack: Wgf[k][f] = sum_c Wq[k,c]*We[f,c] ----
__global__ void k_packg(const float* __restrict__ Wq, const float* __restrict__ bq,
                        const float* __restrict__ We, float* __restrict__ Wgf,
                        float* __restrict__ bgf, int C) {
    int id = blockIdx.x * 256 + threadIdx.x;
    if (id < 2048) {
        int k = id >> 4, f = id & 15;
        float s = 0.f;
        for (int c = 0; c < C; ++c) s = fmaf(Wq[k * C + c], We[f * C + c], s);
        Wgf[id] = s;              // layout [k*16+f]
    } else if (id < 2064) {
        int f = id - 2048;
        float s = 0.f;
        for (int c = 0; c < C; ++c) s = fmaf(bq[c], We[f * C + c], s);
        bgf[f] = s;
    }
}

// ---------------- weight packing (cols: Wq|Wk|Wv|Ws|Wg -> 4C+16) -------------
__global__ void k_packw(const float* __restrict__ Wq, const float* __restrict__ Wk,
                        const float* __restrict__ Wv, const float* __restrict__ Ws,
                        const float* __restrict__ Wgf, ushort* __restrict__ Bp, int C) {
    int nct = (4 * C + 16) >> 4;
    int total = 4 * nct * 512;
    int id = blockIdx.x * 256 + threadIdx.x;
    if (id >= total) return;
    int j = id & 7;
    int rest = id >> 3;
    int lane = rest & 63;
    rest >>= 6;
    int ct = rest % nct;
    int kt = rest / nct;
    int k = kt * 32 + ((lane >> 4) << 3) + j;
    int c = (ct << 4) + (lane & 15);
    float w;
    if (c < 4 * C) {
        int mat = c / C, cc = c % C;
        const float* W = (mat == 0) ? Wq : (mat == 1) ? Wk : (mat == 2) ? Wv : Ws;
        w = W[k * C + cc];
    } else {
        w = Wgf[k * 16 + (c - 4 * C)];
    }
    Bp[id] = f2bf(w);
}

__global__ void k_bias(const float* __restrict__ bq, const float* __restrict__ bk,
                       const float* __restrict__ bv, const float* __restrict__ bs,
                       const float* __restrict__ bgf, float* __restrict__ outp, int C) {
    int c = blockIdx.x * 256 + threadIdx.x;
    if (c >= 4 * C + 16) return;
    float v;
    if (c < 4 * C) {
        int mat = c / C, cc = c % C;
        const float* b = (mat == 0) ? bq : (mat == 1) ? bk : (mat == 2) ? bv : bs;
        v = b[cc];
    } else {
        v = bgf[c - 4 * C];
    }
    outp[c] = v;
}

// ---------------- fused QKVSG GEMM (bf16 MFMA) ----------------
// A: [N,128] bf16. Cols [0,3C)->H (q|k|v), [3C,4C)->S (skip), [4C,4C+16)->g.
__global__ __launch_bounds__(256) void k_gemm(const ushort* __restrict__ A,
                                              const ushort* __restrict__ Bp,
                                              const float* __restrict__ bias,
                                              ushort* __restrict__ H,
                                              ushort* __restrict__ S,
                                              ushort* __restrict__ g, int C) {
    int fourC = 4 * C, threeC = 3 * C;
    int P = fourC + 16;
    int nct = P >> 4;
    int lane = threadIdx.x & 63;
    int wave = threadIdx.x >> 6;
    int quad = lane >> 4;
    int r = lane & 15;
    int m0 = blockIdx.y << 4;
    int c0 = (blockIdx.x << 8) + (wave << 6);
    int ct0 = c0 >> 4;
    if (ct0 >= nct) return;
    int row = m0 + r;                 // N divisible by 16

    f32x4 acc[4];
#pragma unroll
    for (int i = 0; i < 4; ++i) acc[i] = (f32x4){0.f, 0.f, 0.f, 0.f};

#pragma unroll
    for (int kk = 0; kk < 4; ++kk) {
        bf16x8 a = *(const bf16x8*)(A + (size_t)row * 128 + kk * 32 + (quad << 3));
#pragma unroll
        for (int i = 0; i < 4; ++i) {
            if (ct0 + i < nct) {
                bf16x8 b = *(const bf16x8*)(Bp + ((size_t)((kk * nct + ct0 + i) << 6) + lane) * 8);
                acc[i] = __builtin_amdgcn_mfma_f32_16x16x32_bf16(a, b, acc[i], 0, 0, 0);
            }
        }
    }
#pragma unroll
    for (int i = 0; i < 4; ++i) {
        int cc = c0 + (i << 4) + r;
        if (cc >= P) continue;
        float bi = bias[cc];
#pragma unroll
        for (int reg = 0; reg < 4; ++reg) {
            int rr = m0 + (quad << 2) + reg;
            ushort val = f2bf(acc[i][reg] + bi);
            if (cc < threeC)      H[(size_t)rr * threeC + cc] = val;
            else if (cc < fourC)  S[(size_t)rr * C + (cc - threeC)] = val;
            else                  g[(size_t)rr * 16 + (cc - fourC)] = val;
        }
    }
}

// ---------------- edge attention: 16-lane groups, one edge per group ---------
// H: [N,3C] bf16 (q|k|v). S: skip on entry, output on exit. g: [N,16] bf16.
template <int C, bool RELU>
__global__ __launch_bounds__(256) void k_edge(const ushort* __restrict__ H,
                                              ushort* __restrict__ S,
                                              const ushort* __restrict__ g,
                                              const uint* __restrict__ row_ptr,
                                              const int2* __restrict__ srcid,
                                              const float* __restrict__ eattr,
                                              const float* __restrict__ We,
                                              int N, int totalWaves) {
    constexpr int VR = C / 16;      // bf16 per lane per row-chunk (8 or 16)
    constexpr int NU4 = VR / 8;     // uint4 loads per chunk (1 or 2)
    constexpr int TH = 3 * C;
    const float scale = (C == 128) ? 0.08838834764831843f : 0.0625f;  // 1/sqrt(C)
    int lane = threadIdx.x & 63;
    int sub = lane & 15;            // position within group (feature f, col chunk)
    int quad = lane >> 4;           // edge slot within wave
    int gw = (int)((blockIdx.x * blockDim.x + threadIdx.x) >> 6);

    for (int node = gw; node < N; node += totalWaves) {
        uint beg = row_ptr[node], end = row_ptr[node + 1];
        // q (same addresses across the 4 groups -> broadcast)
        float q[VR];
        {
            const uint4* qp = (const uint4*)(H + (size_t)node * TH + sub * VR);
#pragma unroll
            for (int u = 0; u < NU4; ++u) { uint4 tt = qp[u]; unpack8(tt, q + u * 8); }
        }
        float gl = bf2f(g[(size_t)node * 16 + sub]);
        float m = -1e30f, l = 0.f, w = 0.f;
        float acc[VR];
#pragma unroll
        for (int j = 0; j < VR; ++j) acc[j] = 0.f;

        if (beg < end) {
            uint last = end - 1;
            uint i1 = beg + quad;     if (i1 > last) i1 = last;
            uint i2 = beg + 4 + quad; if (i2 > last) i2 = last;
            int2 seA = srcid[i1];
            int2 seB = srcid[i2];
            float atA = eattr[(size_t)seA.y * 16 + sub];
            uint4 kA[NU4], vA[NU4];
            {
                const uint4* kp = (const uint4*)(H + (size_t)seA.x * TH + C + sub * VR);
                const uint4* vp = (const uint4*)(H + (size_t)seA.x * TH + 2 * C + sub * VR);
#pragma unroll
                for (int u = 0; u < NU4; ++u) { kA[u] = kp[u]; vA[u] = vp[u]; }
            }
            for (uint t = beg; t < end; t += 4) {
                // prefetch: srcid for t+8, gathers for t+4
                uint i3 = t + 8 + (uint)quad; if (i3 > last) i3 = last;
                int2 seC = srcid[i3];
                float atB = eattr[(size_t)seB.y * 16 + sub];
                uint4 kB[NU4], vB[NU4];
                {
                    const uint4* kp = (const uint4*)(H + (size_t)seB.x * TH + C + sub * VR);
                    const uint4* vp = (const uint4*)(H + (size_t)seB.x * TH + 2 * C + sub * VR);
#pragma unroll
                    for (int u = 0; u < NU4; ++u) { kB[u] = kp[u]; vB[u] = vp[u]; }
                }
                bool valid = (t + (uint)quad) < end;
                // dot: q.k + attr.g folded into the same 16-lane reduce
                float kf[VR];
#pragma unroll
                for (int u = 0; u < NU4; ++u) unpack8(kA[u], kf + u * 8);
                float p = atA * gl;
#pragma unroll
                for (int j = 0; j < VR; ++j) p = fmaf(q[j], kf[j], p);
                p += __shfl_xor(p, 1);
                p += __shfl_xor(p, 2);
                p += __shfl_xor(p, 4);
                p += __shfl_xor(p, 8);
                float alpha = valid ? p * scale : -1e30f;
                float mn = fmaxf(m, alpha);
                float sc = __expf(m - mn);
                float e = valid ? __expf(alpha - mn) : 0.f;
                l = l * sc + e;
                w = fmaf(e, atA, w * sc);
                float vf[VR];
#pragma unroll
                for (int u = 0; u < NU4; ++u) unpack8(vA[u], vf + u * 8);
#pragma unroll
                for (int j = 0; j < VR; ++j) acc[j] = fmaf(e, vf[j], acc[j] * sc);
                m = mn;
                seB = seC;
                atA = atB;
#pragma unroll
                for (int u = 0; u < NU4; ++u) { kA[u] = kB[u]; vA[u] = vB[u]; }
            }
            // merge the 4 group-local softmax states
            float mm = fmaxf(m, __shfl_xor(m, 16));
            mm = fmaxf(mm, __shfl_xor(mm, 32));
            float r = __expf(m - mm);     // 0 for empty/never-valid groups
            l *= r; l += __shfl_xor(l, 16); l += __shfl_xor(l, 32);
            w *= r; w += __shfl_xor(w, 16); w += __shfl_xor(w, 32);
#pragma unroll
            for (int j = 0; j < VR; ++j) {
                float a = acc[j] * r;
                a += __shfl_xor(a, 16);
                a += __shfl_xor(a, 32);
                acc[j] = a;
            }
        }
        float inv = 1.f / (l + 1e-16f);   // empty node: acc=w=0 -> out = skip
        // ew = (w @ We) for this lane's cols; f-range split across groups
        float ew[VR];
#pragma unroll
        for (int j = 0; j < VR; ++j) ew[j] = 0.f;
#pragma unroll
        for (int i = 0; i < 4; ++i) {
            int f = quad * 4 + i;
            float wf = __shfl(w, f);      // w uniform across groups after merge
            const float* wrow = We + f * C + sub * VR;
#pragma unroll
            for (int u = 0; u < VR / 4; ++u) {
                float4 cv = *(const float4*)(wrow + u * 4);
                ew[u * 4 + 0] = fmaf(wf, cv.x, ew[u * 4 + 0]);
                ew[u * 4 + 1] = fmaf(wf, cv.y, ew[u * 4 + 1]);
                ew[u * 4 + 2] = fmaf(wf, cv.z, ew[u * 4 + 2]);
                ew[u * 4 + 3] = fmaf(wf, cv.w, ew[u * 4 + 3]);
            }
        }
#pragma unroll
        for (int j = 0; j < VR; ++j) {
            ew[j] += __shfl_xor(ew[j], 16);
            ew[j] += __shfl_xor(ew[j], 32);
        }
        if (quad == 0) {                   // 16 lanes store the full row
            ushort* srow = S + (size_t)node * C + sub * VR;
#pragma unroll
            for (int u = 0; u < NU4; ++u) {
                uint4 skv = *(const uint4*)(srow + u * 8);
                float sk[8];
                unpack8(skv, sk);
                uint4 ov;
                uint* op = (uint*)&ov;
#pragma unroll
                for (int h = 0; h < 4; ++h) {
                    float o0 = (acc[u * 8 + 2 * h] + ew[u * 8 + 2 * h]) * inv + sk[2 * h];
                    float o1 = (acc[u * 8 + 2 * h + 1] + ew[u * 8 + 2 * h + 1]) * inv + sk[2 * h + 1];
                    if (RELU) { o0 = fmaxf(o0, 0.f); o1 = fmaxf(o1, 0.f); }
                    op[h] = (uint)f2bf(o0) | ((uint)f2bf(o1) << 16);
                }
                *(uint4*)(srow + u * 8) = ov;
            }
        }
    }
}

// ---------------- classifier: out[N,10] = h3(bf16) @ Wc + bc ----------------
__global__ void k_cls(const ushort* __restrict__ h, const float* __restrict__ Wc,
                      const float* __restrict__ bc, float* __restrict__ outp, int N) {
    int t = blockIdx.x * 256 + threadIdx.x;
    int node = t >> 4;
    int c = t & 15;
    if (node >= N || c >= 10) return;
    const ushort* hr = h + (size_t)node * 256;
    float acc = 0.f;
#pragma unroll 4
    for (int k4 = 0; k4 < 64; ++k4) {
        uint2 u = *(const uint2*)(hr + k4 * 4);
        float h0 = bf2f((ushort)(u.x & 0xffffu));
        float h1 = bf2f((ushort)(u.x >> 16));
        float h2 = bf2f((ushort)(u.y & 0xffffu));
        float h3 = bf2f((ushort)(u.y >> 16));
        int kb = k4 * 4;
        acc = fmaf(h0, Wc[(kb + 0) * 10 + c], acc);
        acc = fmaf(h1, Wc[(kb + 1) * 10 + c], acc);
        acc = fmaf(h2, Wc[(kb + 2) * 10 + c], acc);
        acc = fmaf(h3, Wc[(kb + 3) * 10 + c], acc);
    }
    outp[node * 10 + c] = acc + bc[c];
}

// ---------------- launch ----------------
extern "C" void kernel_launch(void* const* d_in, const int* in_sizes, int n_in,
                              void* d_out, int out_size, void* d_ws, size_t ws_size,
                              hipStream_t stream) {
    const float* x = (const float*)d_in[0];
    const int* ei = (const int*)d_in[1];
    const float* eattr = (const float*)d_in[2];
    const int N = in_sizes[0] / 128;
    const int E = in_sizes[1] / 2;

    const float* Wq[3], *bq[3], *Wk[3], *bk[3], *Wv[3], *bv[3], *We[3], *Ws[3], *bs[3];
    for (int li = 0; li < 3; ++li) {
        int base = 3 + li * 9;
        Wq[li] = (const float*)d_in[base + 0];
        bq[li] = (const float*)d_in[base + 1];
        Wk[li] = (const float*)d_in[base + 2];
        bk[li] = (const float*)d_in[base + 3];
        Wv[li] = (const float*)d_in[base + 4];
        bv[li] = (const float*)d_in[base + 5];
        We[li] = (const float*)d_in[base + 6];
        Ws[li] = (const float*)d_in[base + 7];
        bs[li] = (const float*)d_in[base + 8];
    }
    const float* Wc = (const float*)d_in[30];
    const float* bc = (const float*)d_in[31];

    // workspace carve (~243 MB)
    size_t off = 0;
    char* base = (char*)d_ws;
    auto alloc = [&](size_t bytes) -> void* {
        void* p = base + off;
        off = (off + bytes + 255) & ~(size_t)255;
        return p;
    };
    ushort* SA = (ushort*)alloc((size_t)N * 256 * 2);   // skip/out ping
    ushort* SB = (ushort*)alloc((size_t)N * 128 * 2);   // pong (also xb)
    ushort* H  = (ushort*)alloc((size_t)N * 768 * 2);   // q|k|v (max 3C)
    ushort* gbuf = (ushort*)alloc((size_t)N * 16 * 2);  // g = We.q per node
    ushort* Bp = (ushort*)alloc(140000 * 2);            // packed weights
    float* biasc = (float*)alloc(1040 * 4);
    float* Wgf = (float*)alloc(2048 * 4);
    float* bgf = (float*)alloc(16 * 4);
    uint* row_ptr = (uint*)alloc((size_t)(N + 1) * 4);
    uint* counts = (uint*)alloc((size_t)N * 4);
    uint* cursor = (uint*)alloc((size_t)N * 4);
    uint* bsum = (uint*)alloc(1024 * 4);
    int2* srcid = (int2*)alloc((size_t)E * 8);

    ushort* xb = SB;   // alias: xb dead after layer-1 GEMM

    int nb = (N + 1023) / 1024;

    // CSR build
    k_zero<<<(N + 255) / 256, 256, 0, stream>>>(counts, N);
    k_zero<<<(N + 255) / 256, 256, 0, stream>>>(cursor, N);
    k_hist<<<(E + 255) / 256, 256, 0, stream>>>(ei + E, counts, E, N);
    k_scan1<<<nb, 256, 0, stream>>>(counts, bsum, N);
    k_scan2<<<1, 64, 0, stream>>>(bsum, nb);
    k_scan3<<<nb, 256, 0, stream>>>(counts, bsum, row_ptr, N, E);
    k_fill<<<(E + 255) / 256, 256, 0, stream>>>(ei, row_ptr, cursor, srcid, E, N);

    // x -> bf16
    int n4 = N * 128 / 4;
    k_cvt<<<(n4 + 255) / 256, 256, 0, stream>>>((const float4*)x, (ushort4*)xb, n4);

    const int EDGE_BLOCKS = 2048;
    const int TW = EDGE_BLOCKS * 4;

    for (int li = 0; li < 3; ++li) {
        int C = (li == 2) ? 256 : 128;
        int P = 4 * C + 16;
        int packTotal = 4 * (P >> 4) * 512;
        const ushort* A = (li == 0) ? xb : (li == 1) ? SA : SB;
        ushort* Sout = (li == 1) ? SB : SA;

        k_packg<<<9, 256, 0, stream>>>(Wq[li], bq[li], We[li], Wgf, bgf, C);
        k_packw<<<(packTotal + 255) / 256, 256, 0, stream>>>(Wq[li], Wk[li], Wv[li], Ws[li], Wgf, Bp, C);
        k_bias<<<(P + 255) / 256, 256, 0, stream>>>(bq[li], bk[li], bv[li], bs[li], bgf, biasc, C);
        k_gemm<<<dim3((P + 255) / 256, N / 16), 256, 0, stream>>>(A, Bp, biasc, H, Sout, gbuf, C);
        if (li == 2)
            k_edge<256, false><<<EDGE_BLOCKS, 256, 0, stream>>>(H, Sout, gbuf, row_ptr, srcid, eattr, We[li], N, TW);
        else
            k_edge<128, true><<<EDGE_BLOCKS, 256, 0, stream>>>(H, Sout, gbuf, row_ptr, srcid, eattr, We[li], N, TW);
    }

    // classifier (layer-3 output is in SA)
    k_cls<<<(N * 16 + 255) / 256, 256, 0, stream>>>(SA, Wc, bc, (float*)d_out, N);
}